// Round 15
// baseline (2987.945 us; speedup 1.0000x reference)
//
#include <hip/hip_runtime.h>
#include <hip/hip_bf16.h>

typedef __attribute__((ext_vector_type(4))) float f32x4;
typedef __attribute__((ext_vector_type(8))) short bf16x8;
typedef __attribute__((ext_vector_type(8))) unsigned short us8;
typedef unsigned int   u32;
typedef unsigned short u16;

#define D_DIM 2048
#define I_DIM 768
#define NE    64
#define CAP   1024
#define NTOK  4096

__device__ __forceinline__ u32 cvt2(float a, float b) {
  __hip_bfloat162 hh = __float22bfloat162_rn(float2{a, b});
  union { __hip_bfloat162 h; u32 u; } c; c.h = hh; return c.u;
}
__device__ __forceinline__ u16 f2b(float f) {
  __hip_bfloat16 b = __float2bfloat16(f);
  union { __hip_bfloat16 b; u16 u; } c; c.b = b; return c.u;
}
__device__ __forceinline__ float b2f(u16 v) {
  union { u32 u; float f; } c; c.u = (u32)v << 16; return c.f;
}
// async global->LDS, 16B per lane. LDS dest = wave-uniform base + lane*16.
__device__ __forceinline__ void glp16(const void* g, void* l) {
  __builtin_amdgcn_global_load_lds(
      (const __attribute__((address_space(1))) u32*)g,
      (__attribute__((address_space(3))) u32*)l, 16, 0, 0);
}

#define VMW(n) asm volatile("s_waitcnt vmcnt(" #n ")" ::: "memory")
#define LGK    asm volatile("s_waitcnt lgkmcnt(0)" ::: "memory")
#define BARF   do { __builtin_amdgcn_s_barrier(); \
                    asm volatile("" ::: "memory"); } while (0)

// ---------------- x fp32 -> bf16 ----------------
__global__ __launch_bounds__(256) void k_cvt_x(const float* __restrict__ x,
                                               u16* __restrict__ xb) {
  const size_t i = ((size_t)blockIdx.x * 256 + threadIdx.x) * 8;
  float4 v0 = *(const float4*)(x + i);
  float4 v1 = *(const float4*)(x + i + 4);
  uint4 o;
  o.x = cvt2(v0.x, v0.y); o.y = cvt2(v0.z, v0.w);
  o.z = cvt2(v1.x, v1.y); o.w = cvt2(v1.z, v1.w);
  *(uint4*)(xb + i) = o;
}

// ---------------- router: fp32 logits, top-8, renorm, dispatch ----------------
__global__ __launch_bounds__(256) void k_router(
    const float* __restrict__ x, const float* __restrict__ rw,
    int* __restrict__ counts, int* __restrict__ slot_token,
    float* __restrict__ slot_w)
{
  const int lane = threadIdx.x & 63;
  const int tok  = blockIdx.x * 4 + (threadIdx.x >> 6);
  const float* xr = x + (size_t)tok * D_DIM;

  float acc = 0.f;
  for (int d0 = 0; d0 < D_DIM; d0 += 64) {
    float xv = xr[d0 + lane];
    #pragma unroll
    for (int j = 0; j < 64; ++j) {
      float xj = __shfl(xv, j, 64);
      acc = fmaf(xj, rw[(size_t)(d0 + j) * NE + lane], acc);
    }
  }

  float v = acc; int vi = lane;
  float wk[8]; int ei[8];
  float mx0 = 0.f, wsum = 0.f;
  #pragma unroll
  for (int k = 0; k < 8; ++k) {
    float mv = v; int mi = vi;
    #pragma unroll
    for (int off = 32; off >= 1; off >>= 1) {
      float ov = __shfl_xor(mv, off, 64);
      int   oi = __shfl_xor(mi, off, 64);
      if (ov > mv || (ov == mv && oi < mi)) { mv = ov; mi = oi; }
    }
    if (k == 0) mx0 = mv;
    float ew = __expf(mv - mx0);
    wk[k] = ew; ei[k] = mi; wsum += ew;
    if (lane == mi) v = -3.4e38f;
  }

  if (lane == 0) {
    float inv = 1.f / wsum;
    #pragma unroll
    for (int k = 0; k < 8; ++k) {
      int ee   = ei[k];
      int slot = atomicAdd(&counts[ee], 1);
      if (slot < CAP) {
        slot_token[ee * CAP + slot] = tok;
        slot_w[ee * CAP + slot]     = wk[k] * inv;
      }
    }
  }
}

// ---------------- inverse map: (e,slot) -> per-token index list --------------
__global__ __launch_bounds__(256) void k_inv(
    const int* __restrict__ counts, const int* __restrict__ slot_token,
    int* __restrict__ tok_cnt, int* __restrict__ tok_idx)
{
  const int e = blockIdx.x;
  int cnt = counts[e]; if (cnt > CAP) cnt = CAP;
  for (int s = threadIdx.x; s < cnt; s += 256) {
    const int tok = slot_token[e * CAP + s];
    const int pos = atomicAdd(&tok_cnt[tok], 1);
    if (pos < 8) tok_idx[tok * 8 + pos] = e * CAP + s;
  }
}

// ---------------- weight pack: fp32 [R][C] -> bf16 [C/64][R/8][64][8] per e ----
__global__ __launch_bounds__(256) void k_wpack(const float* __restrict__ in,
                                               u16* __restrict__ outp,
                                               int R, int C) {
  const int e  = blockIdx.z;
  const int c0 = blockIdx.x * 64;
  const int r0 = blockIdx.y * 64;
  const float* ip = in + (size_t)e * R * C;
  u16* op = outp + (size_t)e * (size_t)(C / 64) * (R / 8) * 512
                 + ((size_t)(c0 / 64) * (R / 8) + (r0 / 8)) * 512;

  __shared__ u16 T[64][76];     // T[n][k]
  const int t  = threadIdx.x;
  const int rr = t >> 4;        // 0..15 (k)
  const int cc = (t & 15) * 4;  // 0..60 (n)
  #pragma unroll
  for (int it = 0; it < 4; ++it) {
    const int r = rr + it * 16;
    float4 v = *(const float4*)(ip + (size_t)(r0 + r) * C + c0 + cc);
    T[cc + 0][r] = f2b(v.x);
    T[cc + 1][r] = f2b(v.y);
    T[cc + 2][r] = f2b(v.z);
    T[cc + 3][r] = f2b(v.w);
  }
  __syncthreads();
  const int n = t & 63;
  #pragma unroll
  for (int p = 0; p < 2; ++p) {
    const int c = (t >> 6) + p * 4;           // kcell 0..7
    const u16* s = &T[n][c * 8];
    uint4 o;
    o.x = (u32)s[0] | ((u32)s[1] << 16);
    o.y = (u32)s[2] | ((u32)s[3] << 16);
    o.z = (u32)s[4] | ((u32)s[5] << 16);
    o.w = (u32)s[6] | ((u32)s[7] << 16);
    *(uint4*)(op + ((size_t)c * 64 + n) * 8) = o;
  }
}

// ---------------- x pack: gather tokens -> xeT[e][kcell(256)][1024][8] --------
__global__ __launch_bounds__(256) void k_xpack(
    const u16* __restrict__ xb, const int* __restrict__ counts,
    const int* __restrict__ slot_token, u16* __restrict__ xeT)
{
  const int e   = blockIdx.z;
  const int s0  = blockIdx.y * 64;
  const int kc0 = blockIdx.x * 32;
  int cnt = counts[e]; if (cnt > CAP) cnt = CAP;

  __shared__ u16 T[64][264];
  const int t = threadIdx.x;
  const int r = t >> 2;
  const int q = t & 3;
  const int  tok  = slot_token[e * CAP + s0 + r];
  const bool live = (s0 + r) < cnt;
  const u16* src = xb + (size_t)tok * D_DIM + kc0 * 8;

  #pragma unroll
  for (int it = 0; it < 8; ++it) {
    const int kl = it * 32 + q * 8;
    us8 v = {0, 0, 0, 0, 0, 0, 0, 0};
    if (live) v = *(const us8*)(src + kl);
    *(us8*)&T[r][kl] = v;
  }
  __syncthreads();

  u16* dst = xeT + (size_t)e * 2097152 + (size_t)kc0 * 8192 + (size_t)s0 * 8;
  const int sl = t & 63;
  #pragma unroll
  for (int p = 0; p < 8; ++p) {
    const int c = (t >> 6) + p * 4;
    const u16* s = &T[sl][c * 8];
    uint4 o = *(const uint4*)s;
    *(uint4*)(dst + (size_t)c * 8192 + sl * 8) = o;
  }
}

// ====== GEMMs: 256 thr / 4 waves, 24KB stage, ring-3 depth-2, 2 blocks/CU =====
// Round-12 structure + 1-phase REGISTER PREFETCH: MFMA(stage j-1 from regs)
// overlaps ds_reads(stage j). lgkmcnt(0) before each barrier closes the
// glp-overwrite race.

// ---- mlp1: tile 128m x 128i (gate+up), wave = 64m x 64i x {g,u} ----
struct M1R { bf16x8 a[4]; bf16x8 g[4]; bf16x8 u[4]; };

__device__ __forceinline__ void m1_issue(
    const u16* xeA, const u16* gb, const u16* ub, u16* st,
    int js, int wv, int lane, int m0)
{
  #pragma unroll
  for (int q = 0; q < 6; ++q) {
    const int id = wv * 6 + q;
    const int kc = (id >> 1) & 3;
    const int h  = id & 1;
    const size_t kcA = (size_t)(js * 4 + kc);
    if (id < 8) {
      glp16(xeA + kcA * 8192 + (size_t)(m0 + h * 64 + lane) * 8,
            st + kc * 1024 + h * 512);
    } else if (id < 16) {
      glp16(gb + (size_t)h * 131072 + kcA * 512 + lane * 8,
            st + 4096 + kc * 1024 + h * 512);
    } else {
      glp16(ub + (size_t)h * 131072 + kcA * 512 + lane * 8,
            st + 8192 + kc * 1024 + h * 512);
    }
  }
}

__device__ __forceinline__ void m1_load(
    M1R& r, const u16* st, int gq, int li, int mrow, int icol)
{
  #pragma unroll
  for (int mf = 0; mf < 4; ++mf)
    r.a[mf] = *(const bf16x8*)&st[(gq * 128 + mrow + mf * 16 + li) * 8];
  #pragma unroll
  for (int nf = 0; nf < 4; ++nf) {
    r.g[nf] = *(const bf16x8*)&st[4096 + (gq * 128 + icol + nf * 16 + li) * 8];
    r.u[nf] = *(const bf16x8*)&st[8192 + (gq * 128 + icol + nf * 16 + li) * 8];
  }
}

__device__ __forceinline__ void m1_mma(
    const M1R& r, f32x4 (&ag)[4][4], f32x4 (&au)[4][4])
{
  __builtin_amdgcn_s_setprio(1);
  #pragma unroll
  for (int mf = 0; mf < 4; ++mf)
    #pragma unroll
    for (int nf = 0; nf < 4; ++nf) {
      ag[mf][nf] = __builtin_amdgcn_mfma_f32_16x16x32_bf16(r.a[mf], r.g[nf], ag[mf][nf], 0, 0, 0);
      au[mf][nf] = __builtin_amdgcn_mfma_f32_16x16x32_bf16(r.a[mf], r.u[nf], au[mf][nf], 0, 0, 0);
    }
  __builtin_amdgcn_s_setprio(0);
}

// grid 3072 (8mt x 6nt x 64e), XCD-swizzled (mt fastest in XCD), 72KB dyn LDS.
__global__ __launch_bounds__(256, 2) void k_mlp1p(
    const u16* __restrict__ xeT, const u16* __restrict__ Gpk,
    const u16* __restrict__ Upk, const int* __restrict__ counts,
    u16* __restrict__ hP)
{
  extern __shared__ u16 sm[];          // 3 x 12288 u16 stages
  const int i   = blockIdx.x;
  const int xcd = i & 7;
  const int p   = i >> 3;              // 0..383
  const int mt  = p & 7;
  const int pe  = p >> 3;              // 0..47
  const int val = pe * 8 + xcd;        // 0..383 == e*6 + nt
  const int e   = val / 6;
  const int nt  = val % 6;

  int cnt = counts[e]; if (cnt > CAP) cnt = CAP;
  const int m0 = mt * 128;
  if (m0 >= cnt) return;

  const int t = threadIdx.x;
  const int lane = t & 63, wv = t >> 6;
  const int li = lane & 15, gq = lane >> 4;
  const int mrow = (wv >> 1) * 64, icol = (wv & 1) * 64;

  const u16* xeA = xeT + (size_t)e * 2097152;
  const u16* gb  = Gpk + (size_t)e * 1572864 + (size_t)(nt * 2) * 131072;
  const u16* ub  = Upk + (size_t)e * 1572864 + (size_t)(nt * 2) * 131072;
  u16* hPe = hP + (size_t)e * 786432;

  f32x4 ag[4][4], au[4][4];
  #pragma unroll
  for (int mf = 0; mf < 4; ++mf)
    #pragma unroll
    for (int nf = 0; nf < 4; ++nf) {
      f32x4 z = {0.f, 0.f, 0.f, 0.f};
      ag[mf][nf] = z; au[mf][nf] = z;
    }

  M1R R0, R1;
  int js = 0;

#define M1PH(WAITN, DO_ISS, ISSBUF, LDBUF, RLD, RMM)                      \
  do {                                                                    \
    LGK; VMW(WAITN); BARF;                                                \
    if (DO_ISS) { m1_issue(xeA, gb, ub, sm + (ISSBUF) * 12288, js, wv, lane, m0); ++js; } \
    m1_load(RLD, sm + (LDBUF) * 12288, gq, li, mrow, icol);               \
    if (RMM) m1_mma(*(RMM), ag, au);                                      \
  } while (0)

  // prologue: issue stages 0,1
  m1_issue(xeA, gb, ub, sm,         0, wv, lane, m0);
  m1_issue(xeA, gb, ub, sm + 12288, 1, wv, lane, m0);
  js = 2;

  // i=0: load stage0 into R0, no mma
  M1PH(6, true, 2, 0, R0, (M1R*)0);
  // i=1..60 (10 blocks of 6)
  for (int jt = 0; jt < 10; ++jt) {
    M1PH(6, true, 0, 1, R1, &R0);   // i%6==1
    M1PH(6, true, 1, 2, R0, &R1);   // i%6==2
    M1PH(6, true, 2, 0, R1, &R0);   // i%6==3
    M1PH(6, true, 0, 1, R0, &R1);   // i%6==4
    M1PH(6, true, 1, 2, R1, &R0);   // i%6==5
    M1PH(6, true, 2, 0, R0, &R1);   // i%6==0
  }
  // i=61: issue stage 63 -> buf0; ld buf1 -> R1; mma R0
  M1PH(6, true, 0, 1, R1, &R0);
  // i=62: ld buf2 -> R0; mma R1
  M1PH(6, false, 0, 2, R0, &R1);
  // i=63: ld buf0 -> R1; mma R0
  M1PH(0, false, 0, 0, R1, &R0);
  // final: mma stage 63
  m1_mma(R1, ag, au);
#undef M1PH

  // epilogue: h = silu(g)*u, packed hP[e][ii>>3][slot][ii&7]
  #pragma unroll
  for (int mf = 0; mf < 4; ++mf)
    #pragma unroll
    for (int jj = 0; jj < 4; ++jj) {
      const int slot = m0 + mrow + mf * 16 + gq * 4 + jj;
      #pragma unroll
      for (int nf = 0; nf < 4; ++nf) {
        const int ii = nt * 128 + icol + nf * 16 + li;
        float gg = ag[mf][nf][jj];
        float uu = au[mf][nf][jj];
        hPe[(size_t)(ii >> 3) * 8192 + slot * 8 + (ii & 7)] =
            f2b(gg * uu / (1.f + __expf(-gg)));
      }
    }
}

// ---- mlp2: tile 128m x 256n, wave = 64m x 128n ----
struct M2R { bf16x8 a[4]; bf16x8 b[8]; };

__device__ __forceinline__ void m2_issue(
    const u16* hPe, const u16* dp, u16* st,
    int js, int wv, int lane, int m0)
{
  #pragma unroll
  for (int q = 0; q < 6; ++q) {
    const int id = wv * 6 + q;
    const size_t kcA = (size_t)(js * 4 + ((id < 8) ? ((id >> 1) & 3) : ((id - 8) & 3)));
    if (id < 8) {
      const int kc = (id >> 1) & 3;
      const int h  = id & 1;
      glp16(hPe + kcA * 8192 + (size_t)(m0 + h * 64 + lane) * 8,
            st + kc * 1024 + h * 512);
    } else {
      const int r  = id - 8;
      const int kc = r & 3;
      const int ng = r >> 2;
      glp16(dp + (size_t)ng * 49152 + kcA * 512 + lane * 8,
            st + 4096 + kc * 2048 + ng * 512);
    }
  }
}

__device__ __forceinline__ void m2_load(
    M2R& r, const u16* st, int gq, int li, int mrow, int ncol)
{
  #pragma unroll
  for (int mf = 0; mf < 4; ++mf)
    r.a[mf] = *(const bf16x8*)&st[(gq * 128 + mrow + mf * 16 + li) * 8];
  #pragma unroll
  for (int nf = 0; nf < 8; ++nf)
    r.b[nf] = *(const bf16x8*)&st[4096 + (gq * 256 + ncol + nf * 16 + li) * 8];
}

__device__ __forceinline__ void m2_mma(const M2R& r, f32x4 (&acc)[4][8])
{
  __builtin_amdgcn_s_setprio(1);
  #pragma unroll
  for (int mf = 0; mf < 4; ++mf)
    #pragma unroll
    for (int nf = 0; nf < 8; ++nf)
      acc[mf][nf] = __builtin_amdgcn_mfma_f32_16x16x32_bf16(r.a[mf], r.b[nf], acc[mf][nf], 0, 0, 0);
  __builtin_amdgcn_s_setprio(0);
}

// grid 4096 (8mt x 8nt x 64e), XCD-swizzled, 72KB dyn LDS.
__global__ __launch_bounds__(256, 2) void k_mlp2p(
    const u16* __restrict__ hP, const u16* __restrict__ Dpk,
    const int* __restrict__ counts, const float* __restrict__ slot_w,
    u16* __restrict__ ye)
{
  extern __shared__ u16 sm[];
  const int i   = blockIdx.x;
  const int xcd = i & 7;
  const int p   = i >> 3;              // 0..511
  const int mt  = p & 7;
  const int pe  = p >> 3;              // 0..63
  const int val = pe * 8 + xcd;        // 0..511 == e*8 + nt
  const int e   = val >> 3;
  const int nt  = val & 7;

  int cnt = counts[e]; if (cnt > CAP) cnt = CAP;
  const int m0 = mt * 128;
  if (m0 >= cnt) return;
  const int n0 = nt * 256;

  const int t = threadIdx.x;
  const int lane = t & 63, wv = t >> 6;
  const int li = lane & 15, gq = lane >> 4;
  const int mrow = (wv >> 1) * 64, ncol = (wv & 1) * 128;

  const u16* hPe = hP + (size_t)e * 786432;
  const u16* dp  = Dpk + (size_t)e * 1572864 + (size_t)(nt * 4) * 49152;
  const int eCAP = e * CAP;

  f32x4 acc[4][8];
  #pragma unroll
  for (int mf = 0; mf < 4; ++mf)
    #pragma unroll
    for (int nf = 0; nf < 8; ++nf) { f32x4 z = {0.f,0.f,0.f,0.f}; acc[mf][nf] = z; }

  M2R R0, R1;
  int js = 0;

#define M2PH(WAITN, DO_ISS, ISSBUF, LDBUF, RLD, RMM)                      \
  do {                                                                    \
    LGK; VMW(WAITN); BARF;                                                \
    if (DO_ISS) { m2_issue(hPe, dp, sm + (ISSBUF) * 12288, js, wv, lane, m0); ++js; } \
    m2_load(RLD, sm + (LDBUF) * 12288, gq, li, mrow, ncol);               \
    if (RMM) m2_mma(*(RMM), acc);                                         \
  } while (0)

  m2_issue(hPe, dp, sm,         0, wv, lane, m0);
  m2_issue(hPe, dp, sm + 12288, 1, wv, lane, m0);
  js = 2;

  // i=0
  M2PH(6, true, 2, 0, R0, (M2R*)0);
  // i=1..18 (3 blocks of 6)
  for (int jt = 0; jt < 3; ++jt) {
    M2PH(6, true, 0, 1, R1, &R0);
    M2PH(6, true, 1, 2, R0, &R1);
    M2PH(6, true, 2, 0, R1, &R0);
    M2PH(6, true, 0, 1, R0, &R1);
    M2PH(6, true, 1, 2, R1, &R0);
    M2PH(6, true, 2, 0, R0, &R1);
  }
  // i=19,20,21 (issue stages 21,22,23)
  M2PH(6, true, 0, 1, R1, &R0);
  M2PH(6, true, 1, 2, R0, &R1);
  M2PH(6, true, 2, 0, R1, &R0);
  // i=22: ld buf1 -> R0; mma R1
  M2PH(6, false, 0, 1, R0, &R1);
  // i=23: ld buf2 -> R1; mma R0
  M2PH(0, false, 0, 2, R1, &R0);
  // final: mma stage 23
  m2_mma(R1, acc);
#undef M2PH

  #pragma unroll
  for (int mf = 0; mf < 4; ++mf)
    #pragma unroll
    for (int jj = 0; jj < 4; ++jj) {
      const int slot = m0 + mrow + mf * 16 + gq * 4 + jj;
      if (slot < cnt) {
        const float wgt = slot_w[eCAP + slot];
        u16* yr = ye + (size_t)(eCAP + slot) * D_DIM + n0 + ncol + li;
        #pragma unroll
        for (int nf = 0; nf < 8; ++nf)
          yr[nf * 16] = f2b(wgt * acc[mf][nf][jj]);
      }
    }
}

// ---------------- combine: out[tok] = sum_k ye[tok_idx[tok][k]] --------------
__global__ __launch_bounds__(256) void k_combine(
    const u16* __restrict__ ye, const int* __restrict__ tok_idx,
    const int* __restrict__ tok_cnt, float* __restrict__ out)
{
  const int tok = blockIdx.x;
  const int c0  = threadIdx.x * 8;
  int cnt8 = tok_cnt[tok]; if (cnt8 > 8) cnt8 = 8;

  float s[8] = {0.f, 0.f, 0.f, 0.f, 0.f, 0.f, 0.f, 0.f};
  #pragma unroll
  for (int k = 0; k < 8; ++k) {
    if (k < cnt8) {
      const int idx = tok_idx[tok * 8 + k];
      const us8 v = *(const us8*)(ye + (size_t)idx * D_DIM + c0);
      #pragma unroll
      for (int j = 0; j < 8; ++j) s[j] += b2f(v[j]);
    }
  }
  float4 o0 = {s[0], s[1], s[2], s[3]};
  float4 o1 = {s[4], s[5], s[6], s[7]};
  float* op = out + (size_t)tok * D_DIM + c0;
  *(float4*)op       = o0;
  *(float4*)(op + 4) = o1;
}

extern "C" void kernel_launch(void* const* d_in, const int* in_sizes, int n_in,
                              void* d_out, int out_size, void* d_ws, size_t ws_size,
                              hipStream_t stream) {
  const float* x    = (const float*)d_in[0];
  const float* rw   = (const float*)d_in[1];
  const float* gate = (const float*)d_in[2];
  const float* up   = (const float*)d_in[3];
  const float* down = (const float*)d_in[4];
  float* out = (float*)d_out;

  char* ws = (char*)d_ws;
  int*   counts     = (int*)ws;
  int*   slot_token = (int*)(ws + 1024);
  float* slot_w     = (float*)(ws + 263168);
  u16*   xb         = (u16*)(ws + 525312);
  u16*   hP         = (u16*)(ws + 17302528);          // 100.66 MB
  u16*   Gpk        = (u16*)(ws + 117965824);         // 201.3 MB
  u16*   Upk        = (u16*)(ws + 319292416);         // 201.3 MB
  u16*   xeT        = (u16*)(ws + 520619008);         // 268.4 MB
  u16*   Dpk        = xeT;                            // aliased: written after mlp1
  u16*   ye         = Gpk;                            // aliased: Gpk+Upk dead after mlp1
  int*   tok_cnt    = (int*)(ws + 721945600);         // xeT tail, dead after mlp1
  int*   tok_idx    = (int*)(ws + 721945600 + 16384); // 128 KB

  // allow 72 KB dynamic LDS (host-side attr set; graph-safe)
  hipFuncSetAttribute((const void*)k_mlp1p,
                      hipFuncAttributeMaxDynamicSharedMemorySize, 73728);
  hipFuncSetAttribute((const void*)k_mlp2p,
                      hipFuncAttributeMaxDynamicSharedMemorySize, 73728);

  hipMemsetAsync(counts, 0, NE * sizeof(int), stream);
  hipMemsetAsync(slot_token, 0, (size_t)NE * CAP * sizeof(int), stream);

  k_cvt_x <<<dim3((NTOK * D_DIM) / (256 * 8)), 256, 0, stream>>>(x, xb);
  k_router<<<dim3(NTOK / 4),                   256, 0, stream>>>(x, rw, counts, slot_token, slot_w);

  k_wpack<<<dim3(12, 32, NE), 256, 0, stream>>>(gate, Gpk, D_DIM, I_DIM);
  k_wpack<<<dim3(12, 32, NE), 256, 0, stream>>>(up,   Upk, D_DIM, I_DIM);
  k_xpack<<<dim3(8, 16, NE),  256, 0, stream>>>(xb, counts, slot_token, xeT);
  k_mlp1p<<<dim3(3072), 256, 73728, stream>>>(xeT, Gpk, Upk, counts, hP);

  // xeT (and tail) dead; Gpk/Upk dead -> reuse for tok maps, Dpk, ye
  hipMemsetAsync(tok_cnt, 0, NTOK * sizeof(int), stream);
  k_inv  <<<dim3(NE), 256, 0, stream>>>(counts, slot_token, tok_cnt, tok_idx);
  k_wpack<<<dim3(32, 12, NE), 256, 0, stream>>>(down, Dpk, I_DIM, D_DIM);

  k_mlp2p  <<<dim3(4096), 256, 73728, stream>>>(hP, Dpk, counts, slot_w, ye);
  k_combine<<<dim3(NTOK), 256, 0, stream>>>(ye, tok_idx, tok_cnt, out);
}

// Round 16
// 1173.776 us; speedup vs baseline: 2.5456x; 2.5456x over previous
//
#include <hip/hip_runtime.h>
#include <hip/hip_bf16.h>

typedef __attribute__((ext_vector_type(4))) float f32x4;
typedef __attribute__((ext_vector_type(8))) short bf16x8;
typedef __attribute__((ext_vector_type(8))) unsigned short us8;
typedef unsigned int   u32;
typedef unsigned short u16;

#define D_DIM 2048
#define I_DIM 768
#define NE    64
#define CAP   1024
#define NTOK  4096

__device__ __forceinline__ u32 cvt2(float a, float b) {
  __hip_bfloat162 hh = __float22bfloat162_rn(float2{a, b});
  union { __hip_bfloat162 h; u32 u; } c; c.h = hh; return c.u;
}
__device__ __forceinline__ u16 f2b(float f) {
  __hip_bfloat16 b = __float2bfloat16(f);
  union { __hip_bfloat16 b; u16 u; } c; c.b = b; return c.u;
}
__device__ __forceinline__ float b2f(u16 v) {
  union { u32 u; float f; } c; c.u = (u32)v << 16; return c.f;
}
// async global->LDS, 16B per lane. LDS dest = wave-uniform base + lane*16.
__device__ __forceinline__ void glp16(const void* g, void* l) {
  __builtin_amdgcn_global_load_lds(
      (const __attribute__((address_space(1))) u32*)g,
      (__attribute__((address_space(3))) u32*)l, 16, 0, 0);
}

#define VMW(n) asm volatile("s_waitcnt vmcnt(" #n ")" ::: "memory")
#define BARF   do { __builtin_amdgcn_s_barrier(); \
                    asm volatile("" ::: "memory"); } while (0)

// ---------------- router: fp32 logits, top-8, renorm, dispatch + bf16 x copy --
__global__ __launch_bounds__(256) void k_router(
    const float* __restrict__ x, const float* __restrict__ rw,
    int* __restrict__ counts, int* __restrict__ slot_token,
    float* __restrict__ slot_w, u16* __restrict__ xb)
{
  const int lane = threadIdx.x & 63;
  const int tok  = blockIdx.x * 4 + (threadIdx.x >> 6);
  const float* xr = x + (size_t)tok * D_DIM;
  u16* xbr = xb + (size_t)tok * D_DIM;

  float acc = 0.f;
  for (int d0 = 0; d0 < D_DIM; d0 += 64) {
    float xv = xr[d0 + lane];
    xbr[d0 + lane] = f2b(xv);          // fused bf16 copy (one read of x total)
    #pragma unroll
    for (int j = 0; j < 64; ++j) {
      float xj = __shfl(xv, j, 64);
      acc = fmaf(xj, rw[(size_t)(d0 + j) * NE + lane], acc);
    }
  }

  float v = acc; int vi = lane;
  float wk[8]; int ei[8];
  float mx0 = 0.f, wsum = 0.f;
  #pragma unroll
  for (int k = 0; k < 8; ++k) {
    float mv = v; int mi = vi;
    #pragma unroll
    for (int off = 32; off >= 1; off >>= 1) {
      float ov = __shfl_xor(mv, off, 64);
      int   oi = __shfl_xor(mi, off, 64);
      if (ov > mv || (ov == mv && oi < mi)) { mv = ov; mi = oi; }
    }
    if (k == 0) mx0 = mv;
    float ew = __expf(mv - mx0);
    wk[k] = ew; ei[k] = mi; wsum += ew;
    if (lane == mi) v = -3.4e38f;
  }

  if (lane == 0) {
    float inv = 1.f / wsum;
    #pragma unroll
    for (int k = 0; k < 8; ++k) {
      int ee   = ei[k];
      int slot = atomicAdd(&counts[ee], 1);
      if (slot < CAP) {
        slot_token[ee * CAP + slot] = tok;
        slot_w[ee * CAP + slot]     = wk[k] * inv;
      }
    }
  }
}

// ---------------- inverse map: (e,slot) -> per-token index list --------------
__global__ __launch_bounds__(256) void k_inv(
    const int* __restrict__ counts, const int* __restrict__ slot_token,
    int* __restrict__ tok_cnt, int* __restrict__ tok_idx)
{
  const int e = blockIdx.x;
  int cnt = counts[e]; if (cnt > CAP) cnt = CAP;
  for (int s = threadIdx.x; s < cnt; s += 256) {
    const int tok = slot_token[e * CAP + s];
    const int pos = atomicAdd(&tok_cnt[tok], 1);
    if (pos < 8) tok_idx[tok * 8 + pos] = e * CAP + s;
  }
}

// ---------------- weight pack: fp32 [R][C] -> bf16 [C/64][R/8][64][8] per e ----
__device__ __forceinline__ void wpack_body(const float* __restrict__ ip,
                                           u16* __restrict__ op, int R, int C,
                                           int c0, int r0) {
  __shared__ u16 T[64][76];     // T[n][k]
  const int t  = threadIdx.x;
  const int rr = t >> 4;        // 0..15 (k)
  const int cc = (t & 15) * 4;  // 0..60 (n)
  #pragma unroll
  for (int it = 0; it < 4; ++it) {
    const int r = rr + it * 16;
    float4 v = *(const float4*)(ip + (size_t)(r0 + r) * C + c0 + cc);
    T[cc + 0][r] = f2b(v.x);
    T[cc + 1][r] = f2b(v.y);
    T[cc + 2][r] = f2b(v.z);
    T[cc + 3][r] = f2b(v.w);
  }
  __syncthreads();
  const int n = t & 63;
  #pragma unroll
  for (int p = 0; p < 2; ++p) {
    const int c = (t >> 6) + p * 4;           // kcell 0..7
    const u16* s = &T[n][c * 8];
    uint4 o;
    o.x = (u32)s[0] | ((u32)s[1] << 16);
    o.y = (u32)s[2] | ((u32)s[3] << 16);
    o.z = (u32)s[4] | ((u32)s[5] << 16);
    o.w = (u32)s[6] | ((u32)s[7] << 16);
    *(uint4*)(op + ((size_t)c * 64 + n) * 8) = o;
  }
}

// gate+up in one launch: grid (12, 32, 2*NE); z&1 selects tensor.
__global__ __launch_bounds__(256) void k_wpack_gu(
    const float* __restrict__ g, const float* __restrict__ u,
    u16* __restrict__ og, u16* __restrict__ ou) {
  const int z  = blockIdx.z;
  const int e  = z >> 1;
  const float* in = (z & 1) ? u : g;
  u16* outp       = (z & 1) ? ou : og;
  const int c0 = blockIdx.x * 64;
  const int r0 = blockIdx.y * 64;
  const float* ip = in + (size_t)e * D_DIM * I_DIM;
  u16* op = outp + (size_t)e * (size_t)(I_DIM / 64) * (D_DIM / 8) * 512
                 + ((size_t)(c0 / 64) * (D_DIM / 8) + (r0 / 8)) * 512;
  wpack_body(ip, op, D_DIM, I_DIM, c0, r0);
}

__global__ __launch_bounds__(256) void k_wpack(const float* __restrict__ in,
                                               u16* __restrict__ outp,
                                               int R, int C) {
  const int e  = blockIdx.z;
  const int c0 = blockIdx.x * 64;
  const int r0 = blockIdx.y * 64;
  const float* ip = in + (size_t)e * R * C;
  u16* op = outp + (size_t)e * (size_t)(C / 64) * (R / 8) * 512
                 + ((size_t)(c0 / 64) * (R / 8) + (r0 / 8)) * 512;
  wpack_body(ip, op, R, C, c0, r0);
}

// ---------------- x pack: gather tokens -> xeT[e][kcell(256)][1024][8] --------
// skips 64-slot tiles wholly beyond ceil128(cnt) (mlp1p never reads them)
__global__ __launch_bounds__(256) void k_xpack(
    const u16* __restrict__ xb, const int* __restrict__ counts,
    const int* __restrict__ slot_token, u16* __restrict__ xeT)
{
  const int e   = blockIdx.z;
  const int s0  = blockIdx.y * 64;
  const int kc0 = blockIdx.x * 32;
  int cnt = counts[e]; if (cnt > CAP) cnt = CAP;
  const int lim = (cnt + 127) & ~127;
  if (s0 >= lim) return;

  __shared__ u16 T[64][264];
  const int t = threadIdx.x;
  const int r = t >> 2;
  const int q = t & 3;
  const int  tok  = slot_token[e * CAP + s0 + r];
  const bool live = (s0 + r) < cnt;
  const u16* src = xb + (size_t)tok * D_DIM + kc0 * 8;

  #pragma unroll
  for (int it = 0; it < 8; ++it) {
    const int kl = it * 32 + q * 8;
    us8 v = {0, 0, 0, 0, 0, 0, 0, 0};
    if (live) v = *(const us8*)(src + kl);
    *(us8*)&T[r][kl] = v;
  }
  __syncthreads();

  u16* dst = xeT + (size_t)e * 2097152 + (size_t)kc0 * 8192 + (size_t)s0 * 8;
  const int sl = t & 63;
  #pragma unroll
  for (int p = 0; p < 8; ++p) {
    const int c = (t >> 6) + p * 4;
    const u16* s = &T[sl][c * 8];
    uint4 o = *(const uint4*)s;
    *(uint4*)(dst + (size_t)c * 8192 + sl * 8) = o;
  }
}

// ====== GEMMs: 256 thr / 4 waves, 24KB stage, ring-3 depth-2, 2 blocks/CU =====
// (round-12 structure, verbatim)

// ---- mlp1: tile 128m x 128i (gate+up), wave = 64m x 64i x {g,u} ----
__device__ __forceinline__ void m1_issue(
    const u16* xeA, const u16* gb, const u16* ub, u16* st,
    int js, int wv, int lane, int m0)
{
  #pragma unroll
  for (int q = 0; q < 6; ++q) {
    const int id = wv * 6 + q;
    const int kc = (id >> 1) & 3;
    const int h  = id & 1;
    const size_t kcA = (size_t)(js * 4 + kc);
    if (id < 8) {
      glp16(xeA + kcA * 8192 + (size_t)(m0 + h * 64 + lane) * 8,
            st + kc * 1024 + h * 512);
    } else if (id < 16) {
      glp16(gb + (size_t)h * 131072 + kcA * 512 + lane * 8,
            st + 4096 + kc * 1024 + h * 512);
    } else {
      glp16(ub + (size_t)h * 131072 + kcA * 512 + lane * 8,
            st + 8192 + kc * 1024 + h * 512);
    }
  }
}

__device__ __forceinline__ void m1_step(
    const u16* st, int gq, int li, int mrow, int icol,
    f32x4 (&ag)[4][4], f32x4 (&au)[4][4])
{
  bf16x8 a[4], g[4], u[4];
  #pragma unroll
  for (int mf = 0; mf < 4; ++mf)
    a[mf] = *(const bf16x8*)&st[(gq * 128 + mrow + mf * 16 + li) * 8];
  #pragma unroll
  for (int nf = 0; nf < 4; ++nf) {
    g[nf] = *(const bf16x8*)&st[4096 + (gq * 128 + icol + nf * 16 + li) * 8];
    u[nf] = *(const bf16x8*)&st[8192 + (gq * 128 + icol + nf * 16 + li) * 8];
  }
  #pragma unroll
  for (int mf = 0; mf < 4; ++mf)
    #pragma unroll
    for (int nf = 0; nf < 4; ++nf) {
      ag[mf][nf] = __builtin_amdgcn_mfma_f32_16x16x32_bf16(a[mf], g[nf], ag[mf][nf], 0, 0, 0);
      au[mf][nf] = __builtin_amdgcn_mfma_f32_16x16x32_bf16(a[mf], u[nf], au[mf][nf], 0, 0, 0);
    }
}

// grid 3072 (8mt x 6nt x 64e), XCD-swizzled (mt fastest in XCD), 72KB dyn LDS.
__global__ __launch_bounds__(256, 2) void k_mlp1p(
    const u16* __restrict__ xeT, const u16* __restrict__ Gpk,
    const u16* __restrict__ Upk, const int* __restrict__ counts,
    u16* __restrict__ hP)
{
  extern __shared__ u16 sm[];          // 3 x 12288 u16 stages
  const int i   = blockIdx.x;
  const int xcd = i & 7;
  const int p   = i >> 3;              // 0..383
  const int mt  = p & 7;
  const int pe  = p >> 3;              // 0..47
  const int val = pe * 8 + xcd;        // 0..383 == e*6 + nt
  const int e   = val / 6;
  const int nt  = val % 6;

  int cnt = counts[e]; if (cnt > CAP) cnt = CAP;
  const int m0 = mt * 128;
  if (m0 >= cnt) return;

  const int t = threadIdx.x;
  const int lane = t & 63, wv = t >> 6;
  const int li = lane & 15, gq = lane >> 4;
  const int mrow = (wv >> 1) * 64, icol = (wv & 1) * 64;

  const u16* xeA = xeT + (size_t)e * 2097152;
  const u16* gb  = Gpk + (size_t)e * 1572864 + (size_t)(nt * 2) * 131072;
  const u16* ub  = Upk + (size_t)e * 1572864 + (size_t)(nt * 2) * 131072;
  u16* hPe = hP + (size_t)e * 786432;

  f32x4 ag[4][4], au[4][4];
  #pragma unroll
  for (int mf = 0; mf < 4; ++mf)
    #pragma unroll
    for (int nf = 0; nf < 4; ++nf) {
      f32x4 z = {0.f, 0.f, 0.f, 0.f};
      ag[mf][nf] = z; au[mf][nf] = z;
    }

  m1_issue(xeA, gb, ub, sm,         0, wv, lane, m0);
  m1_issue(xeA, gb, ub, sm + 12288, 1, wv, lane, m0);

  for (int j = 0; j < 62; ++j) {       // 64 K-phases (K=2048, BK=32)
    VMW(6); BARF;
    m1_issue(xeA, gb, ub, sm + ((j + 2) % 3) * 12288, j + 2, wv, lane, m0);
    m1_step(sm + (j % 3) * 12288, gq, li, mrow, icol, ag, au);
  }
  VMW(6); BARF; m1_step(sm + 2 * 12288, gq, li, mrow, icol, ag, au);  // j=62
  VMW(0); BARF; m1_step(sm + 0 * 12288, gq, li, mrow, icol, ag, au);  // j=63

  // epilogue: h = silu(g)*u, packed hP[e][ii>>3][slot][ii&7]; live slots only
  #pragma unroll
  for (int mf = 0; mf < 4; ++mf)
    #pragma unroll
    for (int jj = 0; jj < 4; ++jj) {
      const int slot = m0 + mrow + mf * 16 + gq * 4 + jj;
      if (slot < cnt) {
        #pragma unroll
        for (int nf = 0; nf < 4; ++nf) {
          const int ii = nt * 128 + icol + nf * 16 + li;
          float gg = ag[mf][nf][jj];
          float uu = au[mf][nf][jj];
          hPe[(size_t)(ii >> 3) * 8192 + slot * 8 + (ii & 7)] =
              f2b(gg * uu / (1.f + __expf(-gg)));
        }
      }
    }
}

// ---- mlp2: tile 128m x 256n, wave = 64m x 128n ----
__device__ __forceinline__ void m2_issue(
    const u16* hPe, const u16* dp, u16* st,
    int js, int wv, int lane, int m0)
{
  #pragma unroll
  for (int q = 0; q < 6; ++q) {
    const int id = wv * 6 + q;
    const size_t kcA = (size_t)(js * 4 + ((id < 8) ? ((id >> 1) & 3) : ((id - 8) & 3)));
    if (id < 8) {
      const int kc = (id >> 1) & 3;
      const int h  = id & 1;
      glp16(hPe + kcA * 8192 + (size_t)(m0 + h * 64 + lane) * 8,
            st + kc * 1024 + h * 512);
    } else {
      const int r  = id - 8;
      const int kc = r & 3;
      const int ng = r >> 2;
      glp16(dp + (size_t)ng * 49152 + kcA * 512 + lane * 8,
            st + 4096 + kc * 2048 + ng * 512);
    }
  }
}

__device__ __forceinline__ void m2_step(
    const u16* st, int gq, int li, int mrow, int ncol,
    f32x4 (&acc)[4][8])
{
  bf16x8 a[4], b[8];
  #pragma unroll
  for (int mf = 0; mf < 4; ++mf)
    a[mf] = *(const bf16x8*)&st[(gq * 128 + mrow + mf * 16 + li) * 8];
  #pragma unroll
  for (int nf = 0; nf < 8; ++nf)
    b[nf] = *(const bf16x8*)&st[4096 + (gq * 256 + ncol + nf * 16 + li) * 8];
  #pragma unroll
  for (int mf = 0; mf < 4; ++mf)
    #pragma unroll
    for (int nf = 0; nf < 8; ++nf)
      acc[mf][nf] = __builtin_amdgcn_mfma_f32_16x16x32_bf16(a[mf], b[nf], acc[mf][nf], 0, 0, 0);
}

// grid 4096 (8mt x 8nt x 64e), XCD-swizzled, 72KB dyn LDS.
__global__ __launch_bounds__(256, 2) void k_mlp2p(
    const u16* __restrict__ hP, const u16* __restrict__ Dpk,
    const int* __restrict__ counts, const float* __restrict__ slot_w,
    u16* __restrict__ ye)
{
  extern __shared__ u16 sm[];
  const int i   = blockIdx.x;
  const int xcd = i & 7;
  const int p   = i >> 3;              // 0..511
  const int mt  = p & 7;
  const int pe  = p >> 3;              // 0..63
  const int val = pe * 8 + xcd;        // 0..511 == e*8 + nt
  const int e   = val >> 3;
  const int nt  = val & 7;

  int cnt = counts[e]; if (cnt > CAP) cnt = CAP;
  const int m0 = mt * 128;
  if (m0 >= cnt) return;
  const int n0 = nt * 256;

  const int t = threadIdx.x;
  const int lane = t & 63, wv = t >> 6;
  const int li = lane & 15, gq = lane >> 4;
  const int mrow = (wv >> 1) * 64, ncol = (wv & 1) * 128;

  const u16* hPe = hP + (size_t)e * 786432;
  const u16* dp  = Dpk + (size_t)e * 1572864 + (size_t)(nt * 4) * 49152;
  const int eCAP = e * CAP;

  f32x4 acc[4][8];
  #pragma unroll
  for (int mf = 0; mf < 4; ++mf)
    #pragma unroll
    for (int nf = 0; nf < 8; ++nf) { f32x4 z = {0.f,0.f,0.f,0.f}; acc[mf][nf] = z; }

  m2_issue(hPe, dp, sm,         0, wv, lane, m0);
  m2_issue(hPe, dp, sm + 12288, 1, wv, lane, m0);

  for (int j = 0; j < 22; ++j) {       // 24 K-phases (K=768, BK=32)
    VMW(6); BARF;
    m2_issue(hPe, dp, sm + ((j + 2) % 3) * 12288, j + 2, wv, lane, m0);
    m2_step(sm + (j % 3) * 12288, gq, li, mrow, ncol, acc);
  }
  VMW(6); BARF; m2_step(sm + (22 % 3) * 12288, gq, li, mrow, ncol, acc);  // j=22
  VMW(0); BARF; m2_step(sm + (23 % 3) * 12288, gq, li, mrow, ncol, acc);  // j=23

  #pragma unroll
  for (int mf = 0; mf < 4; ++mf)
    #pragma unroll
    for (int jj = 0; jj < 4; ++jj) {
      const int slot = m0 + mrow + mf * 16 + gq * 4 + jj;
      if (slot < cnt) {
        const float wgt = slot_w[eCAP + slot];
        u16* yr = ye + (size_t)(eCAP + slot) * D_DIM + n0 + ncol + li;
        #pragma unroll
        for (int nf = 0; nf < 8; ++nf)
          yr[nf * 16] = f2b(wgt * acc[mf][nf][jj]);
      }
    }
}

// ---------------- combine: out[tok] = sum_k ye[tok_idx[tok][k]] --------------
__global__ __launch_bounds__(256) void k_combine(
    const u16* __restrict__ ye, const int* __restrict__ tok_idx,
    const int* __restrict__ tok_cnt, float* __restrict__ out)
{
  const int tok = blockIdx.x;
  const int c0  = threadIdx.x * 8;
  int cnt8 = tok_cnt[tok]; if (cnt8 > 8) cnt8 = 8;

  float s[8] = {0.f, 0.f, 0.f, 0.f, 0.f, 0.f, 0.f, 0.f};
  #pragma unroll
  for (int k = 0; k < 8; ++k) {
    if (k < cnt8) {
      const int idx = tok_idx[tok * 8 + k];
      const us8 v = *(const us8*)(ye + (size_t)idx * D_DIM + c0);
      #pragma unroll
      for (int j = 0; j < 8; ++j) s[j] += b2f(v[j]);
    }
  }
  float4 o0 = {s[0], s[1], s[2], s[3]};
  float4 o1 = {s[4], s[5], s[6], s[7]};
  float* op = out + (size_t)tok * D_DIM + c0;
  *(float4*)op       = o0;
  *(float4*)(op + 4) = o1;
}

extern "C" void kernel_launch(void* const* d_in, const int* in_sizes, int n_in,
                              void* d_out, int out_size, void* d_ws, size_t ws_size,
                              hipStream_t stream) {
  const float* x    = (const float*)d_in[0];
  const float* rw   = (const float*)d_in[1];
  const float* gate = (const float*)d_in[2];
  const float* up   = (const float*)d_in[3];
  const float* down = (const float*)d_in[4];
  float* out = (float*)d_out;

  char* ws = (char*)d_ws;
  int*   counts     = (int*)ws;
  int*   slot_token = (int*)(ws + 1024);
  float* slot_w     = (float*)(ws + 263168);
  u16*   xb         = (u16*)(ws + 525312);
  u16*   hP         = (u16*)(ws + 17302528);          // 100.66 MB
  u16*   Gpk        = (u16*)(ws + 117965824);         // 201.3 MB
  u16*   Upk        = (u16*)(ws + 319292416);         // 201.3 MB
  u16*   xeT        = (u16*)(ws + 520619008);         // 268.4 MB
  u16*   Dpk        = xeT;                            // aliased: written after mlp1
  u16*   ye         = Gpk;                            // aliased: Gpk/Upk dead after mlp1
  int*   tok_cnt    = (int*)(ws + 721945600);         // xeT tail, dead after mlp1
  int*   tok_idx    = (int*)(ws + 721945600 + 16384); // 128 KB

  // allow 72 KB dynamic LDS (host-side attr set; graph-safe)
  hipFuncSetAttribute((const void*)k_mlp1p,
                      hipFuncAttributeMaxDynamicSharedMemorySize, 73728);
  hipFuncSetAttribute((const void*)k_mlp2p,
                      hipFuncAttributeMaxDynamicSharedMemorySize, 73728);

  hipMemsetAsync(counts, 0, NE * sizeof(int), stream);
  hipMemsetAsync(slot_token, 0, (size_t)NE * CAP * sizeof(int), stream);

  k_router<<<dim3(NTOK / 4), 256, 0, stream>>>(x, rw, counts, slot_token, slot_w, xb);

  k_wpack_gu<<<dim3(12, 32, 2 * NE), 256, 0, stream>>>(gate, up, Gpk, Upk);
  k_xpack<<<dim3(8, 16, NE), 256, 0, stream>>>(xb, counts, slot_token, xeT);
  k_mlp1p<<<dim3(3072), 256, 73728, stream>>>(xeT, Gpk, Upk, counts, hP);

  // xeT (and tail) dead; Gpk/Upk dead -> reuse for tok maps, Dpk, ye
  hipMemsetAsync(tok_cnt, 0, NTOK * sizeof(int), stream);
  k_inv  <<<dim3(NE), 256, 0, stream>>>(counts, slot_token, tok_cnt, tok_idx);
  k_wpack<<<dim3(32, 12, NE), 256, 0, stream>>>(down, Dpk, I_DIM, D_DIM);

  k_mlp2p  <<<dim3(4096), 256, 73728, stream>>>(hP, Dpk, counts, slot_w, ye);
  k_combine<<<dim3(NTOK), 256, 0, stream>>>(ye, tok_idx, tok_cnt, out);
}